// Round 1
// baseline (650.239 us; speedup 1.0000x reference)
//
#include <hip/hip_runtime.h>
#include <hip/hip_bf16.h>

typedef __bf16 bf16;
typedef bf16 bf16x8 __attribute__((ext_vector_type(8)));
typedef bf16 bf16x4 __attribute__((ext_vector_type(4)));
typedef float f32x4 __attribute__((ext_vector_type(4)));

#define MFMA16(a, b, c) __builtin_amdgcn_mfma_f32_16x16x32_bf16(a, b, c, 0, 0, 0)

static __device__ __forceinline__ bf16 f2b(float f) { return (bf16)f; }
static __device__ __forceinline__ float b2f(bf16 v) { return (float)v; }

// ---------------- fp32 -> bf16 conversion ----------------
__global__ void cvt_f32_bf16(const float* __restrict__ src, bf16* __restrict__ dst, int n4) {
    int i = blockIdx.x * blockDim.x + threadIdx.x;
    if (i >= n4) return;
    float4 v = reinterpret_cast<const float4*>(src)[i];
    bf16x4 o;
    o[0] = f2b(v.x); o[1] = f2b(v.y); o[2] = f2b(v.z); o[3] = f2b(v.w);
    reinterpret_cast<bf16x4*>(dst)[i] = o;
}

// ---------------- RoPE cos/sin table: tbl[s][i] = {cos, sin}(s * theta_i) ----------------
__global__ void rope_table(float2* __restrict__ tbl) {
    int t = blockIdx.x * blockDim.x + threadIdx.x;   // 0 .. 2048*64-1
    int i = t & 63;
    int s = t >> 6;
    float theta = expf(-9.210340371976184f * (float)(2 * i) * (1.0f / 128.0f));
    float freq = (float)s * theta;
    float sv, cv;
    sincosf(freq, &sv, &cv);
    tbl[t] = make_float2(cv, sv);
}

// ---------------- RoPE in-place on [bh][s][128] bf16, pairs (2i, 2i+1) ----------------
__global__ void rope_apply(bf16* __restrict__ X, const float2* __restrict__ tbl, float scale) {
    int t = blockIdx.x * blockDim.x + threadIdx.x;   // 0 .. 2*16*2048*64-1
    int i = t & 63;
    int s = (t >> 6) & 2047;
    size_t base = (size_t)t * 2;
    float2 cs = tbl[(s << 6) | i];
    float xe = b2f(X[base]);
    float xo = b2f(X[base + 1]);
    float oe = (xe * cs.x - xo * cs.y) * scale;
    float oo = (xe * cs.y + xo * cs.x) * scale;
    X[base]     = f2b(oe);
    X[base + 1] = f2b(oo);
}

// ---------------- GEMM: Y[r][n] = sum_m X[r][m] * W[n][m]  (bf16 in, bf16 out) ----------------
// X: [4096][2048], W: [2048][2048].
// MODE 0: Y = [b][h][s][d]  (r = b*2048+s, n = h*128+d)
// MODE 1: Y = [b][h][d][s]  (V transposed)
template <int MODE>
__global__ __launch_bounds__(256) void gemm_qkv(const bf16* __restrict__ X,
                                                const bf16* __restrict__ W,
                                                bf16* __restrict__ Y) {
    const int K = 2048;
    __shared__ bf16 As[128][40];   // +8 pad: 80B row stride -> 2-way (free) bank aliasing
    __shared__ bf16 Bs[128][40];
    const int tid  = threadIdx.x;
    const int lane = tid & 63;
    const int w    = tid >> 6;
    const int wr   = (w >> 1) * 64;
    const int wc   = (w & 1) * 64;
    const int l15  = lane & 15;
    const int l4   = lane >> 4;
    const int rbase = blockIdx.x * 128;
    const int cbase = blockIdx.y * 128;

    f32x4 acc[4][4] = {};

    for (int kt = 0; kt < K; kt += 32) {
        __syncthreads();
#pragma unroll
        for (int ch = 0; ch < 2; ++ch) {
            int c = tid + 256 * ch;            // 0..511 chunk id
            int row = c >> 2;
            int col = (c & 3) * 8;
            *reinterpret_cast<bf16x8*>(&As[row][col]) =
                *reinterpret_cast<const bf16x8*>(&X[(size_t)(rbase + row) * K + kt + col]);
            *reinterpret_cast<bf16x8*>(&Bs[row][col]) =
                *reinterpret_cast<const bf16x8*>(&W[(size_t)(cbase + row) * K + kt + col]);
        }
        __syncthreads();

        bf16x8 af[4], bfr[4];
#pragma unroll
        for (int mi = 0; mi < 4; ++mi)
            af[mi] = *reinterpret_cast<const bf16x8*>(&As[wr + mi * 16 + l15][l4 * 8]);
#pragma unroll
        for (int ni = 0; ni < 4; ++ni)
            bfr[ni] = *reinterpret_cast<const bf16x8*>(&Bs[wc + ni * 16 + l15][l4 * 8]);
#pragma unroll
        for (int mi = 0; mi < 4; ++mi)
#pragma unroll
            for (int ni = 0; ni < 4; ++ni)
                acc[mi][ni] = MFMA16(af[mi], bfr[ni], acc[mi][ni]);
    }

    if (MODE == 0) {
#pragma unroll
        for (int mi = 0; mi < 4; ++mi) {
            int r0 = rbase + wr + mi * 16 + l4 * 4;
#pragma unroll
            for (int ni = 0; ni < 4; ++ni) {
                int n = cbase + wc + ni * 16 + l15;
                int h = n >> 7, d = n & 127;
#pragma unroll
                for (int i = 0; i < 4; ++i) {
                    int r = r0 + i;
                    int b = r >> 11, s = r & 2047;
                    Y[(((size_t)b * 16 + h) * 2048 + s) * 128 + d] = f2b(acc[mi][ni][i]);
                }
            }
        }
    } else {
#pragma unroll
        for (int mi = 0; mi < 4; ++mi) {
            int r0 = rbase + wr + mi * 16 + l4 * 4;   // 4 consecutive rows, same batch
            int b = r0 >> 11, s = r0 & 2047;
#pragma unroll
            for (int ni = 0; ni < 4; ++ni) {
                int n = cbase + wc + ni * 16 + l15;
                int h = n >> 7, d = n & 127;
                bf16x4 o;
#pragma unroll
                for (int i = 0; i < 4; ++i) o[i] = f2b(acc[mi][ni][i]);
                *reinterpret_cast<bf16x4*>(&Y[(((size_t)b * 16 + h) * 128 + d) * 2048 + s]) = o;
            }
        }
    }
}

// ---------------- causal flash attention ----------------
// Q, K: [bh][2048][128] bf16 (Q pre-scaled by 1/sqrt(128), RoPE applied)
// Vt:   [bh][128][2048] bf16 (V transposed)
// out:  [b][s][2048] fp32
__global__ __launch_bounds__(256) void flash_attn(const bf16* __restrict__ Q,
                                                  const bf16* __restrict__ Km,
                                                  const bf16* __restrict__ Vt,
                                                  float* __restrict__ out) {
    __shared__ bf16 Pl[4][16][72];   // per-wave P tile, stride 72 keeps b128 reads 16B-aligned
    const int tid  = threadIdx.x;
    const int lane = tid & 63;
    const int w    = tid >> 6;
    const int l15  = lane & 15;
    const int l4   = lane >> 4;
    const int bx   = blockIdx.x;          // q tile (64 rows)
    const int bh   = blockIdx.y;
    const int b    = bh >> 4, h = bh & 15;
    const int q0   = bx * 64;
    const int qrow = q0 + w * 16;         // this wave's first q row

    const bf16* Qb = Q  + (size_t)bh * 2048 * 128;
    const bf16* Kb = Km + (size_t)bh * 2048 * 128;
    const bf16* Vb = Vt + (size_t)bh * 128 * 2048;

    bf16x8 qf[4];
#pragma unroll
    for (int ks = 0; ks < 4; ++ks)
        qf[ks] = *reinterpret_cast<const bf16x8*>(&Qb[(size_t)(qrow + l15) * 128 + ks * 32 + l4 * 8]);

    f32x4 o[8] = {};
    float mrow[4], lrow[4];
#pragma unroll
    for (int i = 0; i < 4; ++i) { mrow[i] = -1e30f; lrow[i] = 0.0f; }

    for (int kv = 0; kv <= bx; ++kv) {
        const int kvb = kv * 64;
        f32x4 sacc[4] = {};
#pragma unroll
        for (int ns = 0; ns < 4; ++ns) {
#pragma unroll
            for (int ks = 0; ks < 4; ++ks) {
                bf16x8 kf = *reinterpret_cast<const bf16x8*>(
                    &Kb[(size_t)(kvb + ns * 16 + l15) * 128 + ks * 32 + l4 * 8]);
                sacc[ns] = MFMA16(qf[ks], kf, sacc[ns]);
            }
        }
        if (kv == bx) {   // diagonal tile: causal mask
#pragma unroll
            for (int ns = 0; ns < 4; ++ns)
#pragma unroll
                for (int i = 0; i < 4; ++i) {
                    int row = qrow + l4 * 4 + i;
                    int col = kvb + ns * 16 + l15;
                    if (col > row) sacc[ns][i] = -1e30f;
                }
        }
        // online softmax per row (rows owned by lane: (l>>4)*4 + i)
#pragma unroll
        for (int i = 0; i < 4; ++i) {
            float sm = fmaxf(fmaxf(sacc[0][i], sacc[1][i]), fmaxf(sacc[2][i], sacc[3][i]));
            sm = fmaxf(sm, __shfl_xor(sm, 1));
            sm = fmaxf(sm, __shfl_xor(sm, 2));
            sm = fmaxf(sm, __shfl_xor(sm, 4));
            sm = fmaxf(sm, __shfl_xor(sm, 8));
            float nm    = fmaxf(mrow[i], sm);
            float alpha = __expf(mrow[i] - nm);
            mrow[i]     = nm;
            float ps = 0.0f;
#pragma unroll
            for (int ns = 0; ns < 4; ++ns) {
                float p = __expf(sacc[ns][i] - nm);
                sacc[ns][i] = p;
                ps += p;
            }
            ps += __shfl_xor(ps, 1);
            ps += __shfl_xor(ps, 2);
            ps += __shfl_xor(ps, 4);
            ps += __shfl_xor(ps, 8);
            lrow[i] = lrow[i] * alpha + ps;
#pragma unroll
            for (int ds = 0; ds < 8; ++ds) o[ds][i] *= alpha;
        }
        // P -> LDS (bf16), intra-wave only
#pragma unroll
        for (int ns = 0; ns < 4; ++ns)
#pragma unroll
            for (int i = 0; i < 4; ++i)
                Pl[w][l4 * 4 + i][ns * 16 + l15] = f2b(sacc[ns][i]);
        asm volatile("s_waitcnt lgkmcnt(0)" ::: "memory");
        // PV: O += P @ V   (B-frag = contiguous row of Vt)
#pragma unroll
        for (int k2 = 0; k2 < 2; ++k2) {
            bf16x8 pa = *reinterpret_cast<const bf16x8*>(&Pl[w][l15][k2 * 32 + l4 * 8]);
#pragma unroll
            for (int ds = 0; ds < 8; ++ds) {
                bf16x8 vf = *reinterpret_cast<const bf16x8*>(
                    &Vb[(size_t)(ds * 16 + l15) * 2048 + kvb + k2 * 32 + l4 * 8]);
                o[ds] = MFMA16(pa, vf, o[ds]);
            }
        }
    }
    // normalize + store fp32 [b][s][h*128+d]
#pragma unroll
    for (int i = 0; i < 4; ++i) {
        float inv = 1.0f / lrow[i];
        int r = qrow + l4 * 4 + i;
#pragma unroll
        for (int ds = 0; ds < 8; ++ds)
            out[((size_t)b * 2048 + r) * 2048 + h * 128 + ds * 16 + l15] = o[ds][i] * inv;
    }
}

extern "C" void kernel_launch(void* const* d_in, const int* in_sizes, int n_in,
                              void* d_out, int out_size, void* d_ws, size_t ws_size,
                              hipStream_t stream) {
    const float* x  = (const float*)d_in[0];
    const float* Wq = (const float*)d_in[1];
    const float* Wk = (const float*)d_in[2];
    const float* Wv = (const float*)d_in[3];
    float* out = (float*)d_out;
    char* ws = (char*)d_ws;

    bf16* xb   = (bf16*)(ws + 0);          // 16 MB  [4096][2048]
    bf16* wqb  = (bf16*)(ws + 16777216);   // 8 MB
    bf16* wkb  = (bf16*)(ws + 25165824);   // 8 MB
    bf16* wvb  = (bf16*)(ws + 33554432);   // 8 MB
    bf16* Qm   = (bf16*)(ws + 41943040);   // 16 MB [bh][s][d]
    bf16* Km   = (bf16*)(ws + 58720256);   // 16 MB [bh][s][d]
    bf16* Vt   = (bf16*)(ws + 75497472);   // 16 MB [bh][d][s]
    float2* tbl = (float2*)(ws + 92274688); // 1 MB  [s][64] {cos,sin}

    cvt_f32_bf16<<<8192, 256, 0, stream>>>(x, xb, 2097152);
    cvt_f32_bf16<<<4096, 256, 0, stream>>>(Wq, wqb, 1048576);
    cvt_f32_bf16<<<4096, 256, 0, stream>>>(Wk, wkb, 1048576);
    cvt_f32_bf16<<<4096, 256, 0, stream>>>(Wv, wvb, 1048576);
    rope_table<<<512, 256, 0, stream>>>(tbl);

    dim3 gg(32, 16);
    gemm_qkv<0><<<gg, 256, 0, stream>>>(xb, wqb, Qm);
    gemm_qkv<0><<<gg, 256, 0, stream>>>(xb, wkb, Km);
    gemm_qkv<1><<<gg, 256, 0, stream>>>(xb, wvb, Vt);

    rope_apply<<<16384, 256, 0, stream>>>(Qm, tbl, 0.08838834764831845f); // 1/sqrt(128) folded into Q
    rope_apply<<<16384, 256, 0, stream>>>(Km, tbl, 1.0f);

    dim3 ga(32, 32);
    flash_attn<<<ga, 256, 0, stream>>>(Qm, Km, Vt, out);
}

// Round 2
// 352.136 us; speedup vs baseline: 1.8466x; 1.8466x over previous
//
#include <hip/hip_runtime.h>
#include <hip/hip_bf16.h>
#include <stdint.h>

typedef __bf16 bf16;
typedef bf16 bf16x8 __attribute__((ext_vector_type(8)));
typedef bf16 bf16x4 __attribute__((ext_vector_type(4)));
typedef float f32x4 __attribute__((ext_vector_type(4)));

#define MFMA16(a, b, c) __builtin_amdgcn_mfma_f32_16x16x32_bf16(a, b, c, 0, 0, 0)

static __device__ __forceinline__ bf16 f2b(float f) { return (bf16)f; }
static __device__ __forceinline__ float b2f(bf16 v) { return (float)v; }

// async global->LDS, 16B per lane. dst is wave-uniform base; HW adds lane*16.
static __device__ __forceinline__ void gload16(const void* src, void* dst) {
    __builtin_amdgcn_global_load_lds(
        (const __attribute__((address_space(1))) uint32_t*)src,
        (__attribute__((address_space(3))) uint32_t*)dst, 16, 0, 0);
}

// ---------------- fp32 -> bf16 conversion ----------------
__global__ void cvt_f32_bf16(const float* __restrict__ src, bf16* __restrict__ dst, int n4) {
    int i = blockIdx.x * blockDim.x + threadIdx.x;
    if (i >= n4) return;
    float4 v = reinterpret_cast<const float4*>(src)[i];
    bf16x4 o;
    o[0] = f2b(v.x); o[1] = f2b(v.y); o[2] = f2b(v.z); o[3] = f2b(v.w);
    reinterpret_cast<bf16x4*>(dst)[i] = o;
}

// ---------------- RoPE cos/sin table ----------------
__global__ void rope_table(float2* __restrict__ tbl) {
    int t = blockIdx.x * blockDim.x + threadIdx.x;
    int i = t & 63;
    int s = t >> 6;
    float theta = expf(-9.210340371976184f * (float)(2 * i) * (1.0f / 128.0f));
    float freq = (float)s * theta;
    float sv, cv;
    sincosf(freq, &sv, &cv);
    tbl[t] = make_float2(cv, sv);
}

// ---------------- RoPE in-place on [bh][s][128] bf16 ----------------
__global__ void rope_apply(bf16* __restrict__ X, const float2* __restrict__ tbl, float scale) {
    int t = blockIdx.x * blockDim.x + threadIdx.x;
    int i = t & 63;
    int s = (t >> 6) & 2047;
    size_t base = (size_t)t * 2;
    float2 cs = tbl[(s << 6) | i];
    float xe = b2f(X[base]);
    float xo = b2f(X[base + 1]);
    X[base]     = f2b((xe * cs.x - xo * cs.y) * scale);
    X[base + 1] = f2b((xe * cs.y + xo * cs.x) * scale);
}

// ---------------- GEMM (unchanged this round) ----------------
template <int MODE>
__global__ __launch_bounds__(256) void gemm_qkv(const bf16* __restrict__ X,
                                                const bf16* __restrict__ W,
                                                bf16* __restrict__ Y) {
    const int K = 2048;
    __shared__ bf16 As[128][40];
    __shared__ bf16 Bs[128][40];
    const int tid  = threadIdx.x;
    const int lane = tid & 63;
    const int w    = tid >> 6;
    const int wr   = (w >> 1) * 64;
    const int wc   = (w & 1) * 64;
    const int l15  = lane & 15;
    const int l4   = lane >> 4;
    const int rbase = blockIdx.x * 128;
    const int cbase = blockIdx.y * 128;

    f32x4 acc[4][4] = {};

    for (int kt = 0; kt < K; kt += 32) {
        __syncthreads();
#pragma unroll
        for (int ch = 0; ch < 2; ++ch) {
            int c = tid + 256 * ch;
            int row = c >> 2;
            int col = (c & 3) * 8;
            *reinterpret_cast<bf16x8*>(&As[row][col]) =
                *reinterpret_cast<const bf16x8*>(&X[(size_t)(rbase + row) * K + kt + col]);
            *reinterpret_cast<bf16x8*>(&Bs[row][col]) =
                *reinterpret_cast<const bf16x8*>(&W[(size_t)(cbase + row) * K + kt + col]);
        }
        __syncthreads();

        bf16x8 af[4], bfr[4];
#pragma unroll
        for (int mi = 0; mi < 4; ++mi)
            af[mi] = *reinterpret_cast<const bf16x8*>(&As[wr + mi * 16 + l15][l4 * 8]);
#pragma unroll
        for (int ni = 0; ni < 4; ++ni)
            bfr[ni] = *reinterpret_cast<const bf16x8*>(&Bs[wc + ni * 16 + l15][l4 * 8]);
#pragma unroll
        for (int mi = 0; mi < 4; ++mi)
#pragma unroll
            for (int ni = 0; ni < 4; ++ni)
                acc[mi][ni] = MFMA16(af[mi], bfr[ni], acc[mi][ni]);
    }

    if (MODE == 0) {
#pragma unroll
        for (int mi = 0; mi < 4; ++mi) {
            int r0 = rbase + wr + mi * 16 + l4 * 4;
#pragma unroll
            for (int ni = 0; ni < 4; ++ni) {
                int n = cbase + wc + ni * 16 + l15;
                int h = n >> 7, d = n & 127;
#pragma unroll
                for (int i = 0; i < 4; ++i) {
                    int r = r0 + i;
                    int b = r >> 11, s = r & 2047;
                    Y[(((size_t)b * 16 + h) * 2048 + s) * 128 + d] = f2b(acc[mi][ni][i]);
                }
            }
        }
    } else {
#pragma unroll
        for (int mi = 0; mi < 4; ++mi) {
            int r0 = rbase + wr + mi * 16 + l4 * 4;
            int b = r0 >> 11, s = r0 & 2047;
#pragma unroll
            for (int ni = 0; ni < 4; ++ni) {
                int n = cbase + wc + ni * 16 + l15;
                int h = n >> 7, d = n & 127;
                bf16x4 o;
#pragma unroll
                for (int i = 0; i < 4; ++i) o[i] = f2b(acc[mi][ni][i]);
                *reinterpret_cast<bf16x4*>(&Y[(((size_t)b * 16 + h) * 128 + d) * 2048 + s]) = o;
            }
        }
    }
}

// ---------------- causal flash attention v2 ----------------
// Paired q-tiles (job j and 511-j) -> uniform 34 kv-steps/block; 256 blocks.
// K/V tiles double-buffered in LDS via global_load_lds with XOR-swizzled
// global source (linear LDS dest, swizzled ds_read). 4 waves x 32 q-rows.
__global__ __launch_bounds__(256) void flash_attn(const bf16* __restrict__ Q,
                                                  const bf16* __restrict__ Km,
                                                  const bf16* __restrict__ Vt,
                                                  float* __restrict__ out) {
    __shared__ bf16 Ksh[2][64 * 128];    // [kv=64][d=128] rows 256B = 16 slots of 16B
    __shared__ bf16 Vsh[2][128 * 64];    // [d=128][kv=64] rows 128B = 8 slots
    __shared__ bf16 Psh[4][32 * 64];     // per-wave P, swizzled slots, rows 128B

    const int tid  = threadIdx.x;
    const int lane = tid & 63;
    const int w    = tid >> 6;
    const int l15  = lane & 15;
    const int l4   = lane >> 4;

    for (int job = 0; job < 2; ++job) {
        const int j  = (job == 0) ? (int)blockIdx.x : 511 - (int)blockIdx.x;
        const int bh = j >> 4;
        const int qt = j & 15;
        const int b  = bh >> 4, h = bh & 15;
        const bf16* Qb = Q  + (size_t)bh * 2048 * 128;
        const bf16* Kb = Km + (size_t)bh * 2048 * 128;
        const bf16* Vb = Vt + (size_t)bh * 128 * 2048;
        const int q0 = qt * 128;
        const int rw = q0 + w * 32;      // wave's first q row

        // stage K[kvb..kvb+63][0..127] and Vt[0..127][kvb..kvb+63] into buf
        auto stage = [&](int buf, int kvb) {
            char* kd = (char*)Ksh[buf];
            char* vd = (char*)Vsh[buf];
#pragma unroll
            for (int c4 = 0; c4 < 4; ++c4) {
                int c  = w * 4 + c4;
                // K chunk: 4 rows x 16 slots
                int kr = c * 4 + (lane >> 4);
                int ks = (lane & 15) ^ (kr & 7);
                gload16((const char*)Kb + ((size_t)(kvb + kr) * 128 + ks * 8) * 2,
                        kd + c * 1024);
                // V chunk: 8 rows x 8 slots
                int vr = c * 8 + (lane >> 3);
                int vs = (lane & 7) ^ (vr & 7);
                gload16((const char*)Vb + ((size_t)vr * 2048 + kvb + vs * 8) * 2,
                        vd + c * 1024);
            }
        };

        bf16x8 qf[2][4];
#pragma unroll
        for (int qi = 0; qi < 2; ++qi)
#pragma unroll
            for (int ks = 0; ks < 4; ++ks)
                qf[qi][ks] = *reinterpret_cast<const bf16x8*>(
                    &Qb[(size_t)(rw + qi * 16 + l15) * 128 + ks * 32 + l4 * 8]);

        f32x4 o[2][8] = {};
        float mrow[2][4], lrow[2][4];
#pragma unroll
        for (int qi = 0; qi < 2; ++qi)
#pragma unroll
            for (int i = 0; i < 4; ++i) { mrow[qi][i] = -1e30f; lrow[qi][i] = 0.0f; }

        const int n = 2 * qt + 2;
        stage(0, 0);
        __syncthreads();
        int cur = 0;

        for (int t = 0; t < n; ++t) {
            const int kvb = t * 64;
            if (t + 1 < n) stage(1 - cur, kvb + 64);

            const bool active = (kvb <= rw + 31);
            if (active) {
                const char* kb = (const char*)Ksh[cur];
                f32x4 sacc[2][4] = {};
#pragma unroll
                for (int ns = 0; ns < 4; ++ns) {
                    int r = ns * 16 + l15;
#pragma unroll
                    for (int ks = 0; ks < 4; ++ks) {
                        int phys = (ks * 4 + l4) ^ (r & 7);
                        bf16x8 kf = *reinterpret_cast<const bf16x8*>(kb + r * 256 + phys * 16);
                        sacc[0][ns] = MFMA16(qf[0][ks], kf, sacc[0][ns]);
                        sacc[1][ns] = MFMA16(qf[1][ks], kf, sacc[1][ns]);
                    }
                }
                if (kvb + 63 > rw) {   // diagonal region: causal mask
#pragma unroll
                    for (int qi = 0; qi < 2; ++qi)
#pragma unroll
                        for (int ns = 0; ns < 4; ++ns) {
                            int col = kvb + ns * 16 + l15;
#pragma unroll
                            for (int i = 0; i < 4; ++i) {
                                int row = rw + qi * 16 + l4 * 4 + i;
                                if (col > row) sacc[qi][ns][i] = -1e30f;
                            }
                        }
                }
                // online softmax (8 independent row chains) + swizzled P write
                char* pw = (char*)Psh[w];
#pragma unroll
                for (int qi = 0; qi < 2; ++qi)
#pragma unroll
                    for (int i = 0; i < 4; ++i) {
                        float sm = fmaxf(fmaxf(sacc[qi][0][i], sacc[qi][1][i]),
                                         fmaxf(sacc[qi][2][i], sacc[qi][3][i]));
                        sm = fmaxf(sm, __shfl_xor(sm, 1));
                        sm = fmaxf(sm, __shfl_xor(sm, 2));
                        sm = fmaxf(sm, __shfl_xor(sm, 4));
                        sm = fmaxf(sm, __shfl_xor(sm, 8));
                        float nm    = fmaxf(mrow[qi][i], sm);
                        float alpha = __expf(mrow[qi][i] - nm);
                        mrow[qi][i] = nm;
                        float ps = 0.0f;
                        int r = qi * 16 + l4 * 4 + i;
                        int f = r & 7;
#pragma unroll
                        for (int ns = 0; ns < 4; ++ns) {
                            float p = __expf(sacc[qi][ns][i] - nm);
                            ps += p;
                            int col  = ns * 16 + l15;
                            int slot = (col >> 3) ^ f;
                            *(bf16*)(pw + r * 128 + slot * 16 + (col & 7) * 2) = f2b(p);
                        }
                        ps += __shfl_xor(ps, 1);
                        ps += __shfl_xor(ps, 2);
                        ps += __shfl_xor(ps, 4);
                        ps += __shfl_xor(ps, 8);
                        lrow[qi][i] = lrow[qi][i] * alpha + ps;
#pragma unroll
                        for (int ds = 0; ds < 8; ++ds) o[qi][ds][i] *= alpha;
                    }
                asm volatile("s_waitcnt lgkmcnt(0)" ::: "memory");
                __builtin_amdgcn_sched_barrier(0);
                // PV from swizzled Vsh + P
                const char* vb = (const char*)Vsh[cur];
#pragma unroll
                for (int k2 = 0; k2 < 2; ++k2) {
                    bf16x8 pa[2];
#pragma unroll
                    for (int qi = 0; qi < 2; ++qi) {
                        int pr   = qi * 16 + l15;
                        int phys = (k2 * 4 + l4) ^ (pr & 7);
                        pa[qi] = *reinterpret_cast<const bf16x8*>(pw + pr * 128 + phys * 16);
                    }
#pragma unroll
                    for (int ds = 0; ds < 8; ++ds) {
                        int d    = ds * 16 + l15;
                        int phys = (k2 * 4 + l4) ^ (d & 7);
                        bf16x8 vf = *reinterpret_cast<const bf16x8*>(vb + d * 128 + phys * 16);
                        o[0][ds] = MFMA16(pa[0], vf, o[0][ds]);
                        o[1][ds] = MFMA16(pa[1], vf, o[1][ds]);
                    }
                }
            }
            __syncthreads();   // drains vmcnt: next tile staged; syncs buf reuse
            cur ^= 1;
        }

        // epilogue: normalize + store fp32
#pragma unroll
        for (int qi = 0; qi < 2; ++qi)
#pragma unroll
            for (int i = 0; i < 4; ++i) {
                float inv = 1.0f / lrow[qi][i];
                int row = rw + qi * 16 + l4 * 4 + i;
#pragma unroll
                for (int ds = 0; ds < 8; ++ds)
                    out[((size_t)b * 2048 + row) * 2048 + h * 128 + ds * 16 + l15] =
                        o[qi][ds][i] * inv;
            }
        __syncthreads();   // job boundary: all waves done before restaging
    }
}

extern "C" void kernel_launch(void* const* d_in, const int* in_sizes, int n_in,
                              void* d_out, int out_size, void* d_ws, size_t ws_size,
                              hipStream_t stream) {
    const float* x  = (const float*)d_in[0];
    const float* Wq = (const float*)d_in[1];
    const float* Wk = (const float*)d_in[2];
    const float* Wv = (const float*)d_in[3];
    float* out = (float*)d_out;
    char* ws = (char*)d_ws;

    bf16* xb   = (bf16*)(ws + 0);
    bf16* wqb  = (bf16*)(ws + 16777216);
    bf16* wkb  = (bf16*)(ws + 25165824);
    bf16* wvb  = (bf16*)(ws + 33554432);
    bf16* Qm   = (bf16*)(ws + 41943040);
    bf16* Km   = (bf16*)(ws + 58720256);
    bf16* Vt   = (bf16*)(ws + 75497472);
    float2* tbl = (float2*)(ws + 92274688);

    cvt_f32_bf16<<<8192, 256, 0, stream>>>(x, xb, 2097152);
    cvt_f32_bf16<<<4096, 256, 0, stream>>>(Wq, wqb, 1048576);
    cvt_f32_bf16<<<4096, 256, 0, stream>>>(Wk, wkb, 1048576);
    cvt_f32_bf16<<<4096, 256, 0, stream>>>(Wv, wvb, 1048576);
    rope_table<<<512, 256, 0, stream>>>(tbl);

    dim3 gg(32, 16);
    gemm_qkv<0><<<gg, 256, 0, stream>>>(xb, wqb, Qm);
    gemm_qkv<0><<<gg, 256, 0, stream>>>(xb, wkb, Km);
    gemm_qkv<1><<<gg, 256, 0, stream>>>(xb, wvb, Vt);

    rope_apply<<<16384, 256, 0, stream>>>(Qm, tbl, 0.08838834764831845f);
    rope_apply<<<16384, 256, 0, stream>>>(Km, tbl, 1.0f);

    flash_attn<<<256, 256, 0, stream>>>(Qm, Km, Vt, out);
}